// Round 2
// 466.807 us; speedup vs baseline: 1.0202x; 1.0202x over previous
//
#include <hip/hip_runtime.h>
#include <hip/hip_fp16.h>

#define DEVI __device__ __forceinline__

typedef _Float16 f16x8 __attribute__((ext_vector_type(8)));
typedef float f32x4 __attribute__((ext_vector_type(4)));

static DEVI unsigned short f2h_u(float f) {
    _Float16 h = (_Float16)f;
    return __builtin_bit_cast(unsigned short, h);
}
static DEVI float h2f_u(unsigned short u) {
    return (float)__builtin_bit_cast(_Float16, u);
}
static DEVI unsigned pk2(float a, float b) {
    return (unsigned)f2h_u(a) | ((unsigned)f2h_u(b) << 16);
}

// problem constants
// B=32 Q=300 D=256 H=8 C=32 S=8400 levels (80,80)(40,40)(20,20) P=12

// ---------------- kernel 0: weight prep ----------------
__global__ __launch_bounds__(256) void prep_weights(
    const float* __restrict__ W_val, const float* __restrict__ W_off,
    const float* __restrict__ W_attn, const float* __restrict__ W_out,
    const float* __restrict__ b_off, const float* __restrict__ b_attn,
    unsigned short* __restrict__ Wst, unsigned short* __restrict__ Wct,
    unsigned short* __restrict__ Wot, float* __restrict__ cbias)
{
    int idx = blockIdx.x * 256 + threadIdx.x;
    if (idx < 65536) {
        int n = idx >> 8, k = idx & 255;
        Wst[(((n >> 7) * 32 + (k >> 3)) * 128 + (n & 127)) * 8 + (k & 7)] =
            f2h_u(W_val[k * 256 + n]);
    } else if (idx < 65536 + 73728) {
        int j = idx - 65536;
        int n = j >> 8, k = j & 255;
        Wct[j] = f2h_u(n < 192 ? W_off[k * 192 + n] : W_attn[k * 96 + (n - 192)]);
    } else if (idx < 204800) {
        int j = idx - 139264;
        int n = j >> 8, k = j & 255;
        Wot[j] = f2h_u(W_out[k * 256 + n]);
    } else if (idx < 205088) {
        int j = idx - 204800;
        cbias[j] = (j < 192) ? b_off[j] : b_attn[j - 192];
    }
}

// ---------------- fused: P-GEMM (blocks 0..449) + value GEMM (450..4649) ----------------
__global__ __launch_bounds__(256, 2) void fused_gemms(
    const float* __restrict__ hs, const unsigned short* __restrict__ Wct,
    const float* __restrict__ cbias, float* __restrict__ P,
    const float* __restrict__ enc, const unsigned short* __restrict__ Wst,
    const float* __restrict__ bval, unsigned short* __restrict__ val)
{
    __shared__ __align__(16) char smem[65536];
    const int tid  = threadIdx.x;
    const int wave = tid >> 6;
    const int lane = tid & 63;
    const int l15  = lane & 15;
    const int qd   = lane >> 4;

    if (blockIdx.x < 450) {
        // ---- P GEMM: hs(9600x256) @ Wct^T(288x256) + cbias -> P (ldo=288) ----
        constexpr int BN  = 96;
        constexpr int NI  = BN / 16;
        constexpr int LDA = 40;
        constexpr int LDB = 40;
        constexpr int LDC = BN + 4;
        unsigned short* As = (unsigned short*)smem;
        unsigned short* Bs = (unsigned short*)(smem + 64 * LDA * 2);
        float* Cs = (float*)smem;
        const int m0 = (blockIdx.x / 3) * 64;
        const int n0 = (blockIdx.x % 3) * BN;

        f32x4 acc[NI];
#pragma unroll
        for (int i = 0; i < NI; i++) acc[i] = (f32x4){0.f, 0.f, 0.f, 0.f};

#pragma unroll
        for (int kt = 0; kt < 8; kt++) {
#pragma unroll
            for (int i = 0; i < 2; i++) {
                int f = tid + i * 256;
                int row = f >> 3, c4 = f & 7;
                const float4 v = *(const float4*)(hs + (size_t)(m0 + row) * 256 + kt * 32 + c4 * 4);
                uint2 p;
                p.x = pk2(v.x, v.y);
                p.y = pk2(v.z, v.w);
                *(uint2*)&As[row * LDA + c4 * 4] = p;
            }
            for (int f = tid; f < BN * 4; f += 256) {
                int row = f >> 2, ch = f & 3;
                uint4 v = *(const uint4*)(Wct + (size_t)(n0 + row) * 256 + kt * 32 + ch * 8);
                *(uint4*)&Bs[row * LDB + ch * 8] = v;
            }
            __syncthreads();
            f16x8 afr = *(const f16x8*)&As[(wave * 16 + l15) * LDA + qd * 8];
#pragma unroll
            for (int ni = 0; ni < NI; ni++) {
                f16x8 fb = *(const f16x8*)&Bs[(ni * 16 + l15) * LDB + qd * 8];
                acc[ni] = __builtin_amdgcn_mfma_f32_16x16x32_f16(afr, fb, acc[ni], 0, 0, 0);
            }
            __syncthreads();
        }

#pragma unroll
        for (int ni = 0; ni < NI; ni++) {
#pragma unroll
            for (int r = 0; r < 4; r++) {
                Cs[(wave * 16 + qd * 4 + r) * LDC + ni * 16 + l15] = acc[ni][r];
            }
        }
        __syncthreads();
        for (int f = tid; f < 64 * (BN / 4); f += 256) {
            int row = f / (BN / 4), c4 = f % (BN / 4);
            float4 v = *(const float4*)&Cs[row * LDC + c4 * 4];
            const float4 bb = *(const float4*)(cbias + n0 + c4 * 4);
            v.x += bb.x; v.y += bb.y; v.z += bb.z; v.w += bb.w;
            *(float4*)(P + (size_t)(m0 + row) * 288 + n0 + c4 * 4) = v;
        }
    } else {
        // ---- value GEMM: val = f16(enc @ W_val + b_val), 64 rows/block ----
        unsigned short* Bs = (unsigned short*)smem;     // 64 KB
        const size_t m0 = (size_t)(blockIdx.x - 450) * 64;

#pragma unroll
        for (int it = 0; it < 16; ++it) {
            const int c = wave * 16 + it;
            const unsigned short* gp = Wst + c * 512 + lane * 8;
            unsigned short* lp = Bs + c * 512;
            __builtin_amdgcn_global_load_lds(
                (const __attribute__((address_space(1))) void*)gp,
                (__attribute__((address_space(3))) void*)lp, 16, 0, 0);
        }

        const float* arow = enc + (m0 + wave * 16 + l15) * 256 + qd * 8;
        float4 a0[8], a1[8];
#pragma unroll
        for (int kt = 0; kt < 8; ++kt) {
            a0[kt] = *(const float4*)(arow + kt * 32);
            a1[kt] = *(const float4*)(arow + kt * 32 + 4);
        }
        f16x8 af[8];
#pragma unroll
        for (int kt = 0; kt < 8; ++kt) {
            union { f16x8 v; uint4 u; } t;
            t.u.x = pk2(a0[kt].x, a0[kt].y);
            t.u.y = pk2(a0[kt].z, a0[kt].w);
            t.u.z = pk2(a1[kt].x, a1[kt].y);
            t.u.w = pk2(a1[kt].z, a1[kt].w);
            af[kt] = t.v;
        }

        f32x4 acc[2][8];
#pragma unroll
        for (int h = 0; h < 2; ++h)
#pragma unroll
            for (int i = 0; i < 8; ++i) acc[h][i] = (f32x4){0.f, 0.f, 0.f, 0.f};

        __syncthreads();

#pragma unroll
        for (int kt = 0; kt < 8; ++kt) {
#pragma unroll
            for (int ni = 0; ni < 8; ++ni) {
                f16x8 bf = *(const f16x8*)&Bs[(((kt * 4 + qd) * 128) + ni * 16 + l15) * 8];
                acc[0][ni] = __builtin_amdgcn_mfma_f32_16x16x32_f16(af[kt], bf, acc[0][ni], 0, 0, 0);
            }
        }
        __syncthreads();

#pragma unroll
        for (int it = 0; it < 16; ++it) {
            const int c = wave * 16 + it;
            const unsigned short* gp = Wst + 32768 + c * 512 + lane * 8;
            unsigned short* lp = Bs + c * 512;
            __builtin_amdgcn_global_load_lds(
                (const __attribute__((address_space(1))) void*)gp,
                (__attribute__((address_space(3))) void*)lp, 16, 0, 0);
        }
        __syncthreads();
#pragma unroll
        for (int kt = 0; kt < 8; ++kt) {
#pragma unroll
            for (int ni = 0; ni < 8; ++ni) {
                f16x8 bf = *(const f16x8*)&Bs[(((kt * 4 + qd) * 128) + ni * 16 + l15) * 8];
                acc[1][ni] = __builtin_amdgcn_mfma_f32_16x16x32_f16(af[kt], bf, acc[1][ni], 0, 0, 0);
            }
        }

        constexpr int LDH = 136;
#pragma unroll
        for (int h = 0; h < 2; ++h) {
            __syncthreads();
            unsigned short* Ch = Bs;
#pragma unroll
            for (int ni = 0; ni < 8; ++ni) {
                const float bb = bval[h * 128 + ni * 16 + l15];
#pragma unroll
                for (int r = 0; r < 4; ++r) {
                    Ch[(wave * 16 + qd * 4 + r) * LDH + ni * 16 + l15] =
                        f2h_u(acc[h][ni][r] + bb);
                }
            }
            __syncthreads();
            for (int f = tid; f < 64 * 16; f += 256) {
                int row = f >> 4, c8 = f & 15;
                uint4 v = *(uint4*)&Ch[row * LDH + c8 * 8];
                *(uint4*)(val + (m0 + row) * 256 + h * 128 + c8 * 8) = v;
            }
        }
    }
}

// ---------------- fused softmax + loc + bilinear sampling + attn weighting ----------------
// Block = 4 consecutive query-rows of ONE batch b (XCD-affinity swizzle on b).
// Phase 2: 2-deep software pipeline of 12-tap batches (3 points each) with
// statically-named double buffers -> peak live set ~110 VGPR, cap at 4 waves/SIMD.
// Output written as f16 (same rounding point as the downstream GEMM's convert).
__global__ __launch_bounds__(256, 4) void sample_attn(
    const float* __restrict__ P, const float* __restrict__ refp,
    const unsigned short* __restrict__ val, unsigned short* __restrict__ out_attn)
{
    __shared__ float sP[1152];             // 4 rows x 288
    __shared__ float4 sLoc[4][8][12];      // (locx, locy, w, pad)
    const int tid   = threadIdx.x;
    const int blk   = blockIdx.x;
    const int xcd   = blk & 7;
    const int local = blk >> 3;            // [0,300)
    const int b     = xcd + 8 * (local / 75);
    const int q0    = (local % 75) * 4;
    const int row0  = b * 300 + q0;

    // phase 0: stage 4 P-rows (contiguous) into LDS
    {
        const float4* src = (const float4*)(P + (size_t)row0 * 288);
        for (int f = tid; f < 288; f += 256) ((float4*)sP)[f] = src[f];
    }
    __syncthreads();

    // phase 1: 384 (r,h,p) jobs -> softmax weight + location
    for (int j = tid; j < 384; j += 256) {
        const int r = j / 96, rem = j - r * 96;
        const int h = rem / 12, p = rem - h * 12;
        const float* Pr = sP + r * 288;
        const float* Lg = Pr + 192 + h * 12;
        float m = -1e30f;
#pragma unroll
        for (int jj = 0; jj < 12; jj++) m = fmaxf(m, Lg[jj]);
        float s = 0.f;
#pragma unroll
        for (int jj = 0; jj < 12; jj++) s += __expf(Lg[jj] - m);
        const float w = __expf(Lg[p] - m) / s;
        const float4 r4 = *(const float4*)(refp + (size_t)(row0 + r) * 4);
        float4 L;
        L.x = r4.x + Pr[h * 24 + p * 2]     * 0.125f * r4.z;
        L.y = r4.y + Pr[h * 24 + p * 2 + 1] * 0.125f * r4.w;
        L.z = w;
        L.w = 0.f;
        sLoc[r][h][p] = L;
    }
    __syncthreads();

    // phase 2: gather + weight. thread=(r,h,l8), 4 channels.
    const int r  = tid >> 6;
    const int t6 = tid & 63;
    const int h  = t6 >> 3;
    const int l8 = t6 & 7;
    const int row = row0 + r;
    const unsigned short* vb = val + (size_t)b * 8400 * 256 + h * 32 + l8 * 4;

    float a0 = 0.f, a1 = 0.f, a2 = 0.f, a3 = 0.f;

#define ADDR(g, OFF, KW)                                                      \
    _Pragma("unroll")                                                         \
    for (int pp = 0; pp < 3; ++pp) {                                          \
        const int p2   = (g) * 3 + pp;                                        \
        const int lvl  = p2 >> 2;                                             \
        const int W    = (lvl == 0) ? 80 : ((lvl == 1) ? 40 : 20);            \
        const int loff = (lvl == 0) ? 0 : ((lvl == 1) ? 6400 : 8000);         \
        const float4 L = sLoc[r][h][p2];                                      \
        const float px = L.x * (float)W - 0.5f;                               \
        const float py = L.y * (float)W - 0.5f;                               \
        const float x0f = floorf(px), y0f = floorf(py);                       \
        const float fx = px - x0f, fy = py - y0f;                             \
        const int x0 = (int)x0f, y0 = (int)y0f;                               \
        const int x1 = x0 + 1, y1 = y0 + 1;                                   \
        const bool vx0 = (x0 >= 0) && (x0 < W);                               \
        const bool vx1 = (x1 >= 0) && (x1 < W);                               \
        const bool vy0 = (y0 >= 0) && (y0 < W);                               \
        const bool vy1 = (y1 >= 0) && (y1 < W);                               \
        const int x0c = min(max(x0, 0), W - 1), x1c = min(max(x1, 0), W - 1); \
        const int y0c = min(max(y0, 0), W - 1), y1c = min(max(y1, 0), W - 1); \
        KW[pp * 4 + 0] = (vx0 && vy0) ? L.z * (1.f - fx) * (1.f - fy) : 0.f;  \
        KW[pp * 4 + 1] = (vx1 && vy0) ? L.z * fx * (1.f - fy) : 0.f;          \
        KW[pp * 4 + 2] = (vx0 && vy1) ? L.z * (1.f - fx) * fy : 0.f;          \
        KW[pp * 4 + 3] = (vx1 && vy1) ? L.z * fx * fy : 0.f;                  \
        OFF[pp * 4 + 0] = (loff + y0c * W + x0c) * 256;                       \
        OFF[pp * 4 + 1] = (loff + y0c * W + x1c) * 256;                       \
        OFF[pp * 4 + 2] = (loff + y1c * W + x0c) * 256;                       \
        OFF[pp * 4 + 3] = (loff + y1c * W + x1c) * 256;                       \
    }

#define LOADU(U, OFF)                                                         \
    _Pragma("unroll")                                                         \
    for (int t = 0; t < 12; ++t) U[t] = *(const uint2*)(vb + OFF[t]);

#define FMAU(U, KW)                                                           \
    _Pragma("unroll")                                                         \
    for (int t = 0; t < 12; ++t) {                                            \
        const float k = KW[t];                                                \
        a0 = fmaf(k, h2f_u((unsigned short)(U[t].x & 0xffff)), a0);           \
        a1 = fmaf(k, h2f_u((unsigned short)(U[t].x >> 16)),    a1);           \
        a2 = fmaf(k, h2f_u((unsigned short)(U[t].y & 0xffff)), a2);           \
        a3 = fmaf(k, h2f_u((unsigned short)(U[t].y >> 16)),    a3);           \
    }

    int   offA[12], offB[12];
    float kwA[12], kwB[12];
    uint2 uA[12], uB[12];

    ADDR(0, offA, kwA); LOADU(uA, offA);
    ADDR(1, offB, kwB); LOADU(uB, offB);
    FMAU(uA, kwA);
    ADDR(2, offA, kwA); LOADU(uA, offA);
    FMAU(uB, kwB);
    ADDR(3, offB, kwB); LOADU(uB, offB);
    FMAU(uA, kwA);
    FMAU(uB, kwB);

#undef ADDR
#undef LOADU
#undef FMAU

    uint2 o;
    o.x = pk2(a0, a1);
    o.y = pk2(a2, a3);
    *(uint2*)(out_attn + (size_t)row * 256 + h * 32 + l8 * 4) = o;
}

// ---------------- output GEMM: out = f16A(9600x256) @ Wot^T(256x256) + b_out ----------------
__global__ __launch_bounds__(256) void gemm_out(
    const unsigned short* __restrict__ A, const unsigned short* __restrict__ Wt,
    const float* __restrict__ bias, float* __restrict__ outp)
{
    constexpr int BN  = 64;
    constexpr int NI  = 4;
    constexpr int LDA = 40;
    constexpr int LDB = 40;
    constexpr int LDC = BN + 4;
    constexpr int SM1 = 64 * LDA * 2 + BN * LDB * 2;
    constexpr int SM2 = 64 * LDC * 4;
    constexpr int SMEM = SM1 > SM2 ? SM1 : SM2;
    __shared__ __align__(16) char smem[SMEM];
    unsigned short* As = (unsigned short*)smem;
    unsigned short* Bs = (unsigned short*)(smem + 64 * LDA * 2);
    float* Cs = (float*)smem;

    const int tid  = threadIdx.x;
    const int wave = tid >> 6;
    const int lane = tid & 63;
    const int l15  = lane & 15;
    const int qd   = lane >> 4;
    const int m0   = blockIdx.y * 64;
    const int n0   = blockIdx.x * BN;

    f32x4 acc[NI];
#pragma unroll
    for (int i = 0; i < NI; i++) acc[i] = (f32x4){0.f, 0.f, 0.f, 0.f};

#pragma unroll
    for (int kt = 0; kt < 8; kt++) {
        {
            // A already f16: 64 rows x 32 k = 4 KB, one uint4 per thread
            int row = tid >> 2, c8 = tid & 3;
            uint4 v = *(const uint4*)(A + (size_t)(m0 + row) * 256 + kt * 32 + c8 * 8);
            *(uint4*)&As[row * LDA + c8 * 8] = v;
        }
        {
            int row = tid >> 2, ch = tid & 3;
            uint4 v = *(const uint4*)(Wt + (size_t)(n0 + row) * 256 + kt * 32 + ch * 8);
            *(uint4*)&Bs[row * LDB + ch * 8] = v;
        }
        __syncthreads();
        f16x8 afr = *(const f16x8*)&As[(wave * 16 + l15) * LDA + qd * 8];
#pragma unroll
        for (int ni = 0; ni < NI; ni++) {
            f16x8 fb = *(const f16x8*)&Bs[(ni * 16 + l15) * LDB + qd * 8];
            acc[ni] = __builtin_amdgcn_mfma_f32_16x16x32_f16(afr, fb, acc[ni], 0, 0, 0);
        }
        __syncthreads();
    }

#pragma unroll
    for (int ni = 0; ni < NI; ni++) {
#pragma unroll
        for (int r = 0; r < 4; r++) {
            Cs[(wave * 16 + qd * 4 + r) * LDC + ni * 16 + l15] = acc[ni][r];
        }
    }
    __syncthreads();
    for (int f = tid; f < 64 * (BN / 4); f += 256) {
        int row = f / (BN / 4), c4 = f % (BN / 4);
        float4 v = *(const float4*)&Cs[row * LDC + c4 * 4];
        const float4 bb = *(const float4*)(bias + n0 + c4 * 4);
        v.x += bb.x; v.y += bb.y; v.z += bb.z; v.w += bb.w;
        *(float4*)(outp + (size_t)(m0 + row) * 256 + n0 + c4 * 4) = v;
    }
}

extern "C" void kernel_launch(void* const* d_in, const int* in_sizes, int n_in,
                              void* d_out, int out_size, void* d_ws, size_t ws_size,
                              hipStream_t stream)
{
    const float* hs     = (const float*)d_in[0];
    const float* enc    = (const float*)d_in[1];
    const float* refp   = (const float*)d_in[2];
    const float* W_off  = (const float*)d_in[3];
    const float* b_off  = (const float*)d_in[4];
    const float* W_attn = (const float*)d_in[5];
    const float* b_attn = (const float*)d_in[6];
    const float* W_val  = (const float*)d_in[7];
    const float* b_val  = (const float*)d_in[8];
    const float* W_out  = (const float*)d_in[9];
    const float* b_out  = (const float*)d_in[10];
    float* outp = (float*)d_out;

    // workspace layout (bytes)
    char* ws = (char*)d_ws;
    unsigned short* val = (unsigned short*)ws;                 // 137,625,600
    float* P            = (float*)(ws + 137625600);            //  11,059,200
    unsigned short* oat = (unsigned short*)(ws + 148684800);   //   4,915,200 (f16 now)
    unsigned short* Wst = (unsigned short*)(ws + 153600000);   //     131,072
    unsigned short* Wct = (unsigned short*)(ws + 153731072);   //     147,456
    unsigned short* Wot = (unsigned short*)(ws + 153878528);   //     131,072
    float* cbias        = (float*)(ws + 154009600);            //       1,152

    prep_weights<<<802, 256, 0, stream>>>(W_val, W_off, W_attn, W_out,
                                          b_off, b_attn, Wst, Wct, Wot, cbias);
    fused_gemms<<<4650, 256, 0, stream>>>(hs, Wct, cbias, P, enc, Wst, b_val, val);
    sample_attn<<<2400, 256, 0, stream>>>(P, refp, val, oat);
    gemm_out<<<dim3(4, 150), 256, 0, stream>>>(oat, Wot, b_out, outp);
}

// Round 5
// 461.505 us; speedup vs baseline: 1.0319x; 1.0115x over previous
//
// round 5 resubmission of quarter-staged value path (attempt 3; rounds 3-4 were
// container-acquisition failures with no compile/correctness verdict).
#include <hip/hip_runtime.h>
#include <hip/hip_fp16.h>

#define DEVI __device__ __forceinline__

typedef _Float16 f16x8 __attribute__((ext_vector_type(8)));
typedef float f32x4 __attribute__((ext_vector_type(4)));

static DEVI unsigned short f2h_u(float f) {
    _Float16 h = (_Float16)f;
    return __builtin_bit_cast(unsigned short, h);
}
static DEVI float h2f_u(unsigned short u) {
    return (float)__builtin_bit_cast(_Float16, u);
}
static DEVI unsigned pk2(float a, float b) {
    return (unsigned)f2h_u(a) | ((unsigned)f2h_u(b) << 16);
}

// problem constants
// B=32 Q=300 D=256 H=8 C=32 S=8400 levels (80,80)(40,40)(20,20) P=12

// ---------------- kernel 0: weight prep ----------------
// Wst layout: [n-quarter][k-oct][n&63][k&7]  (each 32KB quarter contiguous)
__global__ __launch_bounds__(256) void prep_weights(
    const float* __restrict__ W_val, const float* __restrict__ W_off,
    const float* __restrict__ W_attn, const float* __restrict__ W_out,
    const float* __restrict__ b_off, const float* __restrict__ b_attn,
    unsigned short* __restrict__ Wst, unsigned short* __restrict__ Wct,
    unsigned short* __restrict__ Wot, float* __restrict__ cbias)
{
    int idx = blockIdx.x * 256 + threadIdx.x;
    if (idx < 65536) {
        int n = idx >> 8, k = idx & 255;
        Wst[((n >> 6) * 32 + (k >> 3)) * 512 + (n & 63) * 8 + (k & 7)] =
            f2h_u(W_val[k * 256 + n]);
    } else if (idx < 65536 + 73728) {
        int j = idx - 65536;
        int n = j >> 8, k = j & 255;
        Wct[j] = f2h_u(n < 192 ? W_off[k * 192 + n] : W_attn[k * 96 + (n - 192)]);
    } else if (idx < 204800) {
        int j = idx - 139264;
        int n = j >> 8, k = j & 255;
        Wot[j] = f2h_u(W_out[k * 256 + n]);
    } else if (idx < 205088) {
        int j = idx - 204800;
        cbias[j] = (j < 192) ? b_off[j] : b_attn[j - 192];
    }
}

// ---------------- fused: P-GEMM (blocks 0..449) + value GEMM (450..4649) ----------------
// Value path: quarter-staged Wst (32KB LDS) -> 3 blocks/CU (was 2 @ 64KB),
// per-kt A conversion keeps live f32 staging regs small.
__global__ __launch_bounds__(256, 3) void fused_gemms(
    const float* __restrict__ hs, const unsigned short* __restrict__ Wct,
    const float* __restrict__ cbias, float* __restrict__ P,
    const float* __restrict__ enc, const unsigned short* __restrict__ Wst,
    const float* __restrict__ bval, unsigned short* __restrict__ val)
{
    __shared__ __align__(16) char smem[32768];
    const int tid  = threadIdx.x;
    const int wave = tid >> 6;
    const int lane = tid & 63;
    const int l15  = lane & 15;
    const int qd   = lane >> 4;

    if (blockIdx.x < 450) {
        // ---- P GEMM: hs(9600x256) @ Wct^T(288x256) + cbias -> P (ldo=288) ----
        constexpr int BN  = 96;
        constexpr int NI  = BN / 16;
        constexpr int LDA = 40;
        constexpr int LDB = 40;
        constexpr int LDC = BN + 4;
        unsigned short* As = (unsigned short*)smem;
        unsigned short* Bs = (unsigned short*)(smem + 64 * LDA * 2);
        float* Cs = (float*)smem;
        const int m0 = (blockIdx.x / 3) * 64;
        const int n0 = (blockIdx.x % 3) * BN;

        f32x4 acc[NI];
#pragma unroll
        for (int i = 0; i < NI; i++) acc[i] = (f32x4){0.f, 0.f, 0.f, 0.f};

#pragma unroll
        for (int kt = 0; kt < 8; kt++) {
#pragma unroll
            for (int i = 0; i < 2; i++) {
                int f = tid + i * 256;
                int row = f >> 3, c4 = f & 7;
                const float4 v = *(const float4*)(hs + (size_t)(m0 + row) * 256 + kt * 32 + c4 * 4);
                uint2 p;
                p.x = pk2(v.x, v.y);
                p.y = pk2(v.z, v.w);
                *(uint2*)&As[row * LDA + c4 * 4] = p;
            }
            for (int f = tid; f < BN * 4; f += 256) {
                int row = f >> 2, ch = f & 3;
                uint4 v = *(const uint4*)(Wct + (size_t)(n0 + row) * 256 + kt * 32 + ch * 8);
                *(uint4*)&Bs[row * LDB + ch * 8] = v;
            }
            __syncthreads();
            f16x8 afr = *(const f16x8*)&As[(wave * 16 + l15) * LDA + qd * 8];
#pragma unroll
            for (int ni = 0; ni < NI; ni++) {
                f16x8 fb = *(const f16x8*)&Bs[(ni * 16 + l15) * LDB + qd * 8];
                acc[ni] = __builtin_amdgcn_mfma_f32_16x16x32_f16(afr, fb, acc[ni], 0, 0, 0);
            }
            __syncthreads();
        }

#pragma unroll
        for (int ni = 0; ni < NI; ni++) {
#pragma unroll
            for (int r = 0; r < 4; r++) {
                Cs[(wave * 16 + qd * 4 + r) * LDC + ni * 16 + l15] = acc[ni][r];
            }
        }
        __syncthreads();
        for (int f = tid; f < 64 * (BN / 4); f += 256) {
            int row = f / (BN / 4), c4 = f % (BN / 4);
            float4 v = *(const float4*)&Cs[row * LDC + c4 * 4];
            const float4 bb = *(const float4*)(cbias + n0 + c4 * 4);
            v.x += bb.x; v.y += bb.y; v.z += bb.z; v.w += bb.w;
            *(float4*)(P + (size_t)(m0 + row) * 288 + n0 + c4 * 4) = v;
        }
    } else {
        // ---- value GEMM: val = f16(enc @ W_val + b_val), 64 rows/block ----
        unsigned short* Bs = (unsigned short*)smem;     // 32 KB (one n-quarter)
        const size_t m0 = (size_t)(blockIdx.x - 450) * 64;

        // stage quarter 0: 32 k-oct groups x 512 shorts
#pragma unroll
        for (int i = 0; i < 8; ++i) {
            const int g = wave * 8 + i;
            const unsigned short* gp = Wst + g * 512 + lane * 8;
            unsigned short* lp = Bs + g * 512;
            __builtin_amdgcn_global_load_lds(
                (const __attribute__((address_space(1))) void*)gp,
                (__attribute__((address_space(3))) void*)lp, 16, 0, 0);
        }

        // load + convert A rows (per-kt temporaries only)
        const float* arow = enc + (m0 + wave * 16 + l15) * 256 + qd * 8;
        f16x8 af[8];
#pragma unroll
        for (int kt = 0; kt < 8; ++kt) {
            const float4 x = *(const float4*)(arow + kt * 32);
            const float4 y = *(const float4*)(arow + kt * 32 + 4);
            union { f16x8 v; uint4 u; } t;
            t.u.x = pk2(x.x, x.y);
            t.u.y = pk2(x.z, x.w);
            t.u.z = pk2(y.x, y.y);
            t.u.w = pk2(y.z, y.w);
            af[kt] = t.v;
        }

        f32x4 acc[4][4];
#pragma unroll
        for (int q = 0; q < 4; ++q)
#pragma unroll
            for (int i = 0; i < 4; ++i) acc[q][i] = (f32x4){0.f, 0.f, 0.f, 0.f};

        __syncthreads();

#pragma unroll
        for (int q = 0; q < 4; ++q) {
#pragma unroll
            for (int kt = 0; kt < 8; ++kt) {
#pragma unroll
                for (int ni = 0; ni < 4; ++ni) {
                    f16x8 bf = *(const f16x8*)&Bs[((kt * 4 + qd) * 64 + ni * 16 + l15) * 8];
                    acc[q][ni] = __builtin_amdgcn_mfma_f32_16x16x32_f16(af[kt], bf, acc[q][ni], 0, 0, 0);
                }
            }
            if (q < 3) {
                __syncthreads();   // all MFMA ds_reads of Bs drained before restage
#pragma unroll
                for (int i = 0; i < 8; ++i) {
                    const int g = wave * 8 + i;
                    const unsigned short* gp = Wst + (q + 1) * 16384 + g * 512 + lane * 8;
                    unsigned short* lp = Bs + g * 512;
                    __builtin_amdgcn_global_load_lds(
                        (const __attribute__((address_space(1))) void*)gp,
                        (__attribute__((address_space(3))) void*)lp, 16, 0, 0);
                }
                __syncthreads();   // staging drained before next quarter's ds_reads
            }
        }

        // epilogue: 2 halves of 128 cols via f16 LDS staging (64 x 136 shorts)
        constexpr int LDH = 136;
#pragma unroll
        for (int h = 0; h < 2; ++h) {
            __syncthreads();
            unsigned short* Ch = Bs;
#pragma unroll
            for (int qq = 0; qq < 2; ++qq) {
#pragma unroll
                for (int ni = 0; ni < 4; ++ni) {
                    const float bb = bval[h * 128 + qq * 64 + ni * 16 + l15];
#pragma unroll
                    for (int r = 0; r < 4; ++r) {
                        Ch[(wave * 16 + qd * 4 + r) * LDH + qq * 64 + ni * 16 + l15] =
                            f2h_u(acc[2 * h + qq][ni][r] + bb);
                    }
                }
            }
            __syncthreads();
            for (int f = tid; f < 64 * 16; f += 256) {
                int row = f >> 4, c8 = f & 15;
                uint4 v = *(uint4*)&Ch[row * LDH + c8 * 8];
                *(uint4*)(val + (m0 + row) * 256 + h * 128 + c8 * 8) = v;
            }
        }
    }
}

// ---------------- fused softmax + loc + bilinear sampling + attn weighting ----------------
// Block = 4 consecutive query-rows of ONE batch b (XCD-affinity swizzle on b).
// Phase 2: 2-deep software pipeline of 12-tap batches (3 points each) with
// statically-named double buffers. Output written as f16.
__global__ __launch_bounds__(256, 4) void sample_attn(
    const float* __restrict__ P, const float* __restrict__ refp,
    const unsigned short* __restrict__ val, unsigned short* __restrict__ out_attn)
{
    __shared__ float sP[1152];             // 4 rows x 288
    __shared__ float4 sLoc[4][8][12];      // (locx, locy, w, pad)
    const int tid   = threadIdx.x;
    const int blk   = blockIdx.x;
    const int xcd   = blk & 7;
    const int local = blk >> 3;            // [0,300)
    const int b     = xcd + 8 * (local / 75);
    const int q0    = (local % 75) * 4;
    const int row0  = b * 300 + q0;

    // phase 0: stage 4 P-rows (contiguous) into LDS
    {
        const float4* src = (const float4*)(P + (size_t)row0 * 288);
        for (int f = tid; f < 288; f += 256) ((float4*)sP)[f] = src[f];
    }
    __syncthreads();

    // phase 1: 384 (r,h,p) jobs -> softmax weight + location
    for (int j = tid; j < 384; j += 256) {
        const int r = j / 96, rem = j - r * 96;
        const int h = rem / 12, p = rem - h * 12;
        const float* Pr = sP + r * 288;
        const float* Lg = Pr + 192 + h * 12;
        float m = -1e30f;
#pragma unroll
        for (int jj = 0; jj < 12; jj++) m = fmaxf(m, Lg[jj]);
        float s = 0.f;
#pragma unroll
        for (int jj = 0; jj < 12; jj++) s += __expf(Lg[jj] - m);
        const float w = __expf(Lg[p] - m) / s;
        const float4 r4 = *(const float4*)(refp + (size_t)(row0 + r) * 4);
        float4 L;
        L.x = r4.x + Pr[h * 24 + p * 2]     * 0.125f * r4.z;
        L.y = r4.y + Pr[h * 24 + p * 2 + 1] * 0.125f * r4.w;
        L.z = w;
        L.w = 0.f;
        sLoc[r][h][p] = L;
    }
    __syncthreads();

    // phase 2: gather + weight. thread=(r,h,l8), 4 channels.
    const int r  = tid >> 6;
    const int t6 = tid & 63;
    const int h  = t6 >> 3;
    const int l8 = t6 & 7;
    const int row = row0 + r;
    const unsigned short* vb = val + (size_t)b * 8400 * 256 + h * 32 + l8 * 4;

    float a0 = 0.f, a1 = 0.f, a2 = 0.f, a3 = 0.f;

#define ADDR(g, OFF, KW)                                                      \
    _Pragma("unroll")                                                         \
    for (int pp = 0; pp < 3; ++pp) {                                          \
        const int p2   = (g) * 3 + pp;                                        \
        const int lvl  = p2 >> 2;                                             \
        const int W    = (lvl == 0) ? 80 : ((lvl == 1) ? 40 : 20);            \
        const int loff = (lvl == 0) ? 0 : ((lvl == 1) ? 6400 : 8000);         \
        const float4 L = sLoc[r][h][p2];                                      \
        const float px = L.x * (float)W - 0.5f;                               \
        const float py = L.y * (float)W - 0.5f;                               \
        const float x0f = floorf(px), y0f = floorf(py);                       \
        const float fx = px - x0f, fy = py - y0f;                             \
        const int x0 = (int)x0f, y0 = (int)y0f;                               \
        const int x1 = x0 + 1, y1 = y0 + 1;                                   \
        const bool vx0 = (x0 >= 0) && (x0 < W);                               \
        const bool vx1 = (x1 >= 0) && (x1 < W);                               \
        const bool vy0 = (y0 >= 0) && (y0 < W);                               \
        const bool vy1 = (y1 >= 0) && (y1 < W);                               \
        const int x0c = min(max(x0, 0), W - 1), x1c = min(max(x1, 0), W - 1); \
        const int y0c = min(max(y0, 0), W - 1), y1c = min(max(y1, 0), W - 1); \
        KW[pp * 4 + 0] = (vx0 && vy0) ? L.z * (1.f - fx) * (1.f - fy) : 0.f;  \
        KW[pp * 4 + 1] = (vx1 && vy0) ? L.z * fx * (1.f - fy) : 0.f;          \
        KW[pp * 4 + 2] = (vx0 && vy1) ? L.z * (1.f - fx) * fy : 0.f;          \
        KW[pp * 4 + 3] = (vx1 && vy1) ? L.z * fx * fy : 0.f;                  \
        OFF[pp * 4 + 0] = (loff + y0c * W + x0c) * 256;                       \
        OFF[pp * 4 + 1] = (loff + y0c * W + x1c) * 256;                       \
        OFF[pp * 4 + 2] = (loff + y1c * W + x0c) * 256;                       \
        OFF[pp * 4 + 3] = (loff + y1c * W + x1c) * 256;                       \
    }

#define LOADU(U, OFF)                                                         \
    _Pragma("unroll")                                                         \
    for (int t = 0; t < 12; ++t) U[t] = *(const uint2*)(vb + OFF[t]);

#define FMAU(U, KW)                                                           \
    _Pragma("unroll")                                                         \
    for (int t = 0; t < 12; ++t) {                                            \
        const float k = KW[t];                                                \
        a0 = fmaf(k, h2f_u((unsigned short)(U[t].x & 0xffff)), a0);           \
        a1 = fmaf(k, h2f_u((unsigned short)(U[t].x >> 16)),    a1);           \
        a2 = fmaf(k, h2f_u((unsigned short)(U[t].y & 0xffff)), a2);           \
        a3 = fmaf(k, h2f_u((unsigned short)(U[t].y >> 16)),    a3);           \
    }

    int   offA[12], offB[12];
    float kwA[12], kwB[12];
    uint2 uA[12], uB[12];

    ADDR(0, offA, kwA); LOADU(uA, offA);
    ADDR(1, offB, kwB); LOADU(uB, offB);
    FMAU(uA, kwA);
    ADDR(2, offA, kwA); LOADU(uA, offA);
    FMAU(uB, kwB);
    ADDR(3, offB, kwB); LOADU(uB, offB);
    FMAU(uA, kwA);
    FMAU(uB, kwB);

#undef ADDR
#undef LOADU
#undef FMAU

    uint2 o;
    o.x = pk2(a0, a1);
    o.y = pk2(a2, a3);
    *(uint2*)(out_attn + (size_t)row * 256 + h * 32 + l8 * 4) = o;
}

// ---------------- output GEMM: out = f16A(9600x256) @ Wot^T(256x256) + b_out ----------------
__global__ __launch_bounds__(256) void gemm_out(
    const unsigned short* __restrict__ A, const unsigned short* __restrict__ Wt,
    const float* __restrict__ bias, float* __restrict__ outp)
{
    constexpr int BN  = 64;
    constexpr int NI  = 4;
    constexpr int LDA = 40;
    constexpr int LDB = 40;
    constexpr int LDC = BN + 4;
    constexpr int SM1 = 64 * LDA * 2 + BN * LDB * 2;
    constexpr int SM2 = 64 * LDC * 4;
    constexpr int SMEM = SM1 > SM2 ? SM1 : SM2;
    __shared__ __align__(16) char smem[SMEM];
    unsigned short* As = (unsigned short*)smem;
    unsigned short* Bs = (unsigned short*)(smem + 64 * LDA * 2);
    float* Cs = (float*)smem;

    const int tid  = threadIdx.x;
    const int wave = tid >> 6;
    const int lane = tid & 63;
    const int l15  = lane & 15;
    const int qd   = lane >> 4;
    const int m0   = blockIdx.y * 64;
    const int n0   = blockIdx.x * BN;

    f32x4 acc[NI];
#pragma unroll
    for (int i = 0; i < NI; i++) acc[i] = (f32x4){0.f, 0.f, 0.f, 0.f};

#pragma unroll
    for (int kt = 0; kt < 8; kt++) {
        {
            // A already f16: 64 rows x 32 k = 4 KB, one uint4 per thread
            int row = tid >> 2, c8 = tid & 3;
            uint4 v = *(const uint4*)(A + (size_t)(m0 + row) * 256 + kt * 32 + c8 * 8);
            *(uint4*)&As[row * LDA + c8 * 8] = v;
        }
        {
            int row = tid >> 2, ch = tid & 3;
            uint4 v = *(const uint4*)(Wt + (size_t)(n0 + row) * 256 + kt * 32 + ch * 8);
            *(uint4*)&Bs[row * LDB + ch * 8] = v;
        }
        __syncthreads();
        f16x8 afr = *(const f16x8*)&As[(wave * 16 + l15) * LDA + qd * 8];
#pragma unroll
        for (int ni = 0; ni < NI; ni++) {
            f16x8 fb = *(const f16x8*)&Bs[(ni * 16 + l15) * LDB + qd * 8];
            acc[ni] = __builtin_amdgcn_mfma_f32_16x16x32_f16(afr, fb, acc[ni], 0, 0, 0);
        }
        __syncthreads();
    }

#pragma unroll
    for (int ni = 0; ni < NI; ni++) {
#pragma unroll
        for (int r = 0; r < 4; r++) {
            Cs[(wave * 16 + qd * 4 + r) * LDC + ni * 16 + l15] = acc[ni][r];
        }
    }
    __syncthreads();
    for (int f = tid; f < 64 * (BN / 4); f += 256) {
        int row = f / (BN / 4), c4 = f % (BN / 4);
        float4 v = *(const float4*)&Cs[row * LDC + c4 * 4];
        const float4 bb = *(const float4*)(bias + n0 + c4 * 4);
        v.x += bb.x; v.y += bb.y; v.z += bb.z; v.w += bb.w;
        *(float4*)(outp + (size_t)(m0 + row) * 256 + n0 + c4 * 4) = v;
    }
}

extern "C" void kernel_launch(void* const* d_in, const int* in_sizes, int n_in,
                              void* d_out, int out_size, void* d_ws, size_t ws_size,
                              hipStream_t stream)
{
    const float* hs     = (const float*)d_in[0];
    const float* enc    = (const float*)d_in[1];
    const float* refp   = (const float*)d_in[2];
    const float* W_off  = (const float*)d_in[3];
    const float* b_off  = (const float*)d_in[4];
    const float* W_attn = (const float*)d_in[5];
    const float* b_attn = (const float*)d_in[6];
    const float* W_val  = (const float*)d_in[7];
    const float* b_val  = (const float*)d_in[8];
    const float* W_out  = (const float*)d_in[9];
    const float* b_out  = (const float*)d_in[10];
    float* outp = (float*)d_out;

    // workspace layout (bytes)
    char* ws = (char*)d_ws;
    unsigned short* val = (unsigned short*)ws;                 // 137,625,600
    float* P            = (float*)(ws + 137625600);            //  11,059,200
    unsigned short* oat = (unsigned short*)(ws + 148684800);   //   4,915,200 (f16)
    unsigned short* Wst = (unsigned short*)(ws + 153600000);   //     131,072
    unsigned short* Wct = (unsigned short*)(ws + 153731072);   //     147,456
    unsigned short* Wot = (unsigned short*)(ws + 153878528);   //     131,072
    float* cbias        = (float*)(ws + 154009600);            //       1,152

    prep_weights<<<802, 256, 0, stream>>>(W_val, W_off, W_attn, W_out,
                                          b_off, b_attn, Wst, Wct, Wot, cbias);
    fused_gemms<<<4650, 256, 0, stream>>>(hs, Wct, cbias, P, enc, Wst, b_val, val);
    sample_attn<<<2400, 256, 0, stream>>>(P, refp, val, oat);
    gemm_out<<<dim3(4, 150), 256, 0, stream>>>(oat, Wot, b_out, outp);
}